// Round 1
// baseline (1025.632 us; speedup 1.0000x reference)
//
#include <hip/hip_runtime.h>

#define KT 4
#define KN 20000        // NA == ND == 20000
#define KE 100000
#define KH 128
#define KL 2
#define KNT 40000       // NA + ND

// ---------------------------------------------------------------------------
// CSR build: counts -> scan -> fill.  cursors array doubles as counts.
// ---------------------------------------------------------------------------
__global__ void count_k(const int* __restrict__ ei_ad, const int* __restrict__ ei_da,
                        int* __restrict__ cnt) {
    int e = blockIdx.x * 256 + threadIdx.x;
    int z = blockIdx.y;                 // z = t*2 + et
    if (e >= KE) return;
    int t = z >> 1, et = z & 1;
    const int* ei = et ? ei_da : ei_ad;
    int dst = ei[(t * 2 + 1) * KE + e];
    atomicAdd(&cnt[z * KN + dst], 1);
}

__global__ void scan_k(int* __restrict__ cnt, int* __restrict__ offs) {
    __shared__ int s[256];
    int z = blockIdx.x, tid = threadIdx.x;
    const int CH = (KN + 255) / 256;    // 79
    int n0 = tid * CH;
    int lim = n0 < KN ? min(CH, KN - n0) : 0;
    long base = (long)z * KN + n0;
    int sum = 0;
    for (int i = 0; i < lim; ++i) sum += cnt[base + i];
    s[tid] = sum;
    __syncthreads();
    for (int off = 1; off < 256; off <<= 1) {
        int v = (tid >= off) ? s[tid - off] : 0;
        __syncthreads();
        s[tid] += v;
        __syncthreads();
    }
    int run = s[tid] - sum;             // exclusive prefix
    for (int i = 0; i < lim; ++i) {
        int c = cnt[base + i];
        offs[(long)z * (KN + 1) + n0 + i] = run;
        cnt[base + i] = run;            // becomes fill cursor
        run += c;
    }
    if (tid == 0) offs[(long)z * (KN + 1) + KN] = KE;
}

__global__ void fill_k(const int* __restrict__ ei_ad, const int* __restrict__ ei_da,
                       int* __restrict__ cur, int* __restrict__ eidx) {
    int e = blockIdx.x * 256 + threadIdx.x;
    int z = blockIdx.y;
    if (e >= KE) return;
    int t = z >> 1, et = z & 1;
    const int* ei = et ? ei_da : ei_ad;
    int dst = ei[(t * 2 + 1) * KE + e];
    int pos = atomicAdd(&cur[z * KN + dst], 1);
    eidx[(long)z * KE + pos] = e;
}

// ---------------------------------------------------------------------------
// Aggregation: one wave per destination node.
// agg[z][n][:] = (1+eps) * x_dst[n][:] + sum_{e in CSR(n)} relu(x_src[src(e)] + ea[e])
// ---------------------------------------------------------------------------
__global__ __launch_bounds__(256)
void agg_k(const float* __restrict__ xa_base, long xa_ts,
           const float* __restrict__ xd_base, long xd_ts,
           const float* __restrict__ ea_ad, const float* __restrict__ ea_da,
           const int* __restrict__ ei_ad, const int* __restrict__ ei_da,
           const float* __restrict__ eps_ad, const float* __restrict__ eps_da,
           const int* __restrict__ offs, const int* __restrict__ eidx,
           float* __restrict__ agg, int l) {
    int z = blockIdx.y, t = z >> 1, et = z & 1;
    int wv = threadIdx.x >> 6, lane = threadIdx.x & 63;
    int node = blockIdx.x * 4 + wv;
    if (node >= KN) return;

    const float* ea   = (et ? ea_da : ea_ad) + (long)t * KE * KH;
    const int*   ei_s = (et ? ei_da : ei_ad) + (long)(t * 2) * KE;   // src row
    const float* eps  = et ? eps_da : eps_ad;
    const float* src  = et ? (xd_base + t * xd_ts) : (xa_base + t * xa_ts);
    const float* dst  = et ? (xa_base + t * xa_ts) : (xd_base + t * xd_ts);

    float scale = 1.0f + eps[t * KL + l];
    const float2* dr = (const float2*)(dst + (long)node * KH);
    float2 acc = dr[lane];
    acc.x *= scale; acc.y *= scale;

    int beg = offs[(long)z * (KN + 1) + node];
    int end = offs[(long)z * (KN + 1) + node + 1];
    for (int i = beg; i < end; ++i) {
        int e = eidx[(long)z * KE + i];
        int s = ei_s[e];
        const float2* xr = (const float2*)(src + (long)s * KH);
        const float2* er = (const float2*)(ea + (long)e * KH);
        float2 a = xr[lane], b = er[lane];
        acc.x += fmaxf(a.x + b.x, 0.0f);
        acc.y += fmaxf(a.y + b.y, 0.0f);
    }
    ((float2*)(agg + ((long)z * KN + node) * KH))[lane] = acc;
}

// ---------------------------------------------------------------------------
// GEMM: out = [relu](H @ W + b).  H is (KN x 128) slice of agg for this z.
// mode 0: write in-place into agg.  mode 1: write to d_out region for (t, et).
// Tile: 128 rows x 128 cols per block, 256 threads, 8x8 micro-tile.
// W (64KB) + transposed 32-wide H chunk (16.9KB) in LDS.
// ---------------------------------------------------------------------------
__global__ __launch_bounds__(256)
void gemm_k(const float* agg,
            const float* __restrict__ w_ad, const float* __restrict__ w_da,
            const float* __restrict__ b_ad, const float* __restrict__ b_da,
            float* out_agg, float* d_out,
            int l, int relu, int mode) {
    __shared__ float lw[KH * KH];       // 64 KB
    __shared__ float hT[32][132];       // 16.9 KB, padded stride

    int z = blockIdx.y, t = z >> 1, et = z & 1;
    int tid = threadIdx.x;
    const float* W = (et ? w_da : w_ad) + (long)(t * KL + l) * KH * KH;
    const float* B = (et ? b_da : b_ad) + (long)(t * KL + l) * KH;
    const float* in = agg + (long)z * KN * KH;

    // stage W (coalesced float4)
    #pragma unroll
    for (int i = 0; i < 16; ++i) {
        int idx = (i * 256 + tid) * 4;
        *(float4*)&lw[idx] = *(const float4*)&W[idx];
    }

    int r0 = blockIdx.x * 128;
    int tx = tid & 15, ty = tid >> 4;
    float acc[8][8];
    #pragma unroll
    for (int i = 0; i < 8; ++i)
        #pragma unroll
        for (int j = 0; j < 8; ++j) acc[i][j] = 0.0f;

    for (int kc = 0; kc < 4; ++kc) {
        // stage transposed H chunk: hT[k - kc*32][row]
        {
            int rr = tid >> 3, kg = tid & 7;
            int k = kc * 32 + kg * 4;
            #pragma unroll
            for (int p = 0; p < 4; ++p) {
                int row = p * 32 + rr;
                float4 v = make_float4(0.f, 0.f, 0.f, 0.f);
                if (r0 + row < KN) v = *(const float4*)&in[(long)(r0 + row) * KH + k];
                hT[kg * 4 + 0][row] = v.x;
                hT[kg * 4 + 1][row] = v.y;
                hT[kg * 4 + 2][row] = v.z;
                hT[kg * 4 + 3][row] = v.w;
            }
        }
        __syncthreads();
        #pragma unroll 4
        for (int kk = 0; kk < 32; ++kk) {
            int k = kc * 32 + kk;
            float4 w0 = *(float4*)&lw[k * KH + tx * 8];
            float4 w1 = *(float4*)&lw[k * KH + tx * 8 + 4];
            float4 h0 = *(float4*)&hT[kk][ty * 8];
            float4 h1 = *(float4*)&hT[kk][ty * 8 + 4];
            float hv[8] = {h0.x, h0.y, h0.z, h0.w, h1.x, h1.y, h1.z, h1.w};
            float wv[8] = {w0.x, w0.y, w0.z, w0.w, w1.x, w1.y, w1.z, w1.w};
            #pragma unroll
            for (int i = 0; i < 8; ++i)
                #pragma unroll
                for (int j = 0; j < 8; ++j)
                    acc[i][j] = fmaf(hv[i], wv[j], acc[i][j]);
        }
        __syncthreads();
    }

    // epilogue
    float bias[8];
    #pragma unroll
    for (int j = 0; j < 8; ++j) bias[j] = B[tx * 8 + j];

    #pragma unroll
    for (int i = 0; i < 8; ++i) {
        int row = r0 + ty * 8 + i;
        if (row >= KN) continue;
        float v[8];
        #pragma unroll
        for (int j = 0; j < 8; ++j) {
            v[j] = acc[i][j] + bias[j];
            if (relu) v[j] = fmaxf(v[j], 0.0f);
        }
        float* orow;
        if (mode == 0) {
            orow = out_agg + ((long)z * KN + row) * KH;
        } else {
            long off = (long)t * KNT * KH + (et == 0 ? (long)KN * KH : 0) + (long)row * KH;
            orow = d_out + off;
        }
        *(float4*)&orow[tx * 8 + 0] = make_float4(v[0], v[1], v[2], v[3]);
        *(float4*)&orow[tx * 8 + 4] = make_float4(v[4], v[5], v[6], v[7]);
    }
}

// ---------------------------------------------------------------------------
extern "C" void kernel_launch(void* const* d_in, const int* in_sizes, int n_in,
                              void* d_out_v, int out_size, void* d_ws, size_t ws_size,
                              hipStream_t stream) {
    const float* x_a    = (const float*)d_in[0];
    const float* x_d    = (const float*)d_in[1];
    const float* ea_ad  = (const float*)d_in[2];
    const float* ea_da  = (const float*)d_in[3];
    const int*   ei_ad  = (const int*)d_in[4];
    const int*   ei_da  = (const int*)d_in[5];
    const float* w1_ad  = (const float*)d_in[6];
    const float* b1_ad  = (const float*)d_in[7];
    const float* w2_ad  = (const float*)d_in[8];
    const float* b2_ad  = (const float*)d_in[9];
    const float* eps_ad = (const float*)d_in[10];
    const float* w1_da  = (const float*)d_in[11];
    const float* b1_da  = (const float*)d_in[12];
    const float* w2_da  = (const float*)d_in[13];
    const float* b2_da  = (const float*)d_in[14];
    const float* eps_da = (const float*)d_in[15];
    float* out = (float*)d_out_v;

    // workspace layout
    float* agg  = (float*)d_ws;                          // 8 * KN * KH floats
    int*   offs = (int*)(agg + (size_t)8 * KN * KH);     // 8 * (KN+1)
    int*   cur  = offs + (size_t)8 * (KN + 1);           // 8 * KN
    int*   eidx = cur + (size_t)8 * KN;                  // 8 * KE

    // ---- build CSR (per z = t*2+et), valid for both layers ----
    hipMemsetAsync(cur, 0, (size_t)8 * KN * sizeof(int), stream);
    dim3 eg((KE + 255) / 256, 8);
    count_k<<<eg, 256, 0, stream>>>(ei_ad, ei_da, cur);
    scan_k<<<8, 256, 0, stream>>>(cur, offs);
    fill_k<<<eg, 256, 0, stream>>>(ei_ad, ei_da, cur, eidx);

    dim3 ag((KN + 3) / 4, 8);
    dim3 gg((KN + 127) / 128, 8);

    for (int l = 0; l < KL; ++l) {
        const float* xab; long xats;
        const float* xdb; long xdts;
        if (l == 0) {
            xab = x_a; xats = (long)KN * KH;
            xdb = x_d; xdts = (long)KN * KH;
        } else {
            xab = out;                 xats = (long)KNT * KH;
            xdb = out + (long)KN * KH; xdts = (long)KNT * KH;
        }
        agg_k<<<ag, 256, 0, stream>>>(xab, xats, xdb, xdts,
                                      ea_ad, ea_da, ei_ad, ei_da,
                                      eps_ad, eps_da, offs, eidx, agg, l);
        // mid = relu(H @ w1 + b1), in-place into agg
        gemm_k<<<gg, 256, 0, stream>>>(agg, w1_ad, w1_da, b1_ad, b1_da,
                                       agg, out, l, 1, 0);
        // x_new = mid @ w2 + b2 (+relu between layers), into d_out
        gemm_k<<<gg, 256, 0, stream>>>(agg, w2_ad, w2_da, b2_ad, b2_da,
                                       agg, out, l, (l == 0) ? 1 : 0, 1);
    }
}

// Round 2
// 715.242 us; speedup vs baseline: 1.4340x; 1.4340x over previous
//
#include <hip/hip_runtime.h>

#define KT 4
#define KN 20000        // NA == ND == 20000
#define KE 100000
#define KH 128
#define KL 2
#define KNT 40000       // NA + ND

// ---------------------------------------------------------------------------
// CSR build: counts -> scan -> fill.  cursors array doubles as counts.
// fill stores packed (edge, src) pairs so agg needs no dependent index chase.
// ---------------------------------------------------------------------------
__global__ void count_k(const int* __restrict__ ei_ad, const int* __restrict__ ei_da,
                        int* __restrict__ cnt) {
    int e = blockIdx.x * 256 + threadIdx.x;
    int z = blockIdx.y;                 // z = t*2 + et
    if (e >= KE) return;
    int t = z >> 1, et = z & 1;
    const int* ei = et ? ei_da : ei_ad;
    int dst = ei[(t * 2 + 1) * KE + e];
    atomicAdd(&cnt[z * KN + dst], 1);
}

__global__ void scan_k(int* __restrict__ cnt, int* __restrict__ offs) {
    __shared__ int s[256];
    int z = blockIdx.x, tid = threadIdx.x;
    const int CH = (KN + 255) / 256;    // 79
    int n0 = tid * CH;
    int lim = n0 < KN ? min(CH, KN - n0) : 0;
    long base = (long)z * KN + n0;
    int sum = 0;
    for (int i = 0; i < lim; ++i) sum += cnt[base + i];
    s[tid] = sum;
    __syncthreads();
    for (int off = 1; off < 256; off <<= 1) {
        int v = (tid >= off) ? s[tid - off] : 0;
        __syncthreads();
        s[tid] += v;
        __syncthreads();
    }
    int run = s[tid] - sum;             // exclusive prefix
    for (int i = 0; i < lim; ++i) {
        int c = cnt[base + i];
        offs[(long)z * (KN + 1) + n0 + i] = run;
        cnt[base + i] = run;            // becomes fill cursor
        run += c;
    }
    if (tid == 0) offs[(long)z * (KN + 1) + KN] = KE;
}

__global__ void fill_k(const int* __restrict__ ei_ad, const int* __restrict__ ei_da,
                       int* __restrict__ cur, int2* __restrict__ pes) {
    int e = blockIdx.x * 256 + threadIdx.x;
    int z = blockIdx.y;
    if (e >= KE) return;
    int t = z >> 1, et = z & 1;
    const int* ei = et ? ei_da : ei_ad;
    int src = ei[(t * 2 + 0) * KE + e];
    int dst = ei[(t * 2 + 1) * KE + e];
    int pos = atomicAdd(&cur[z * KN + dst], 1);
    pes[(long)z * KE + pos] = make_int2(e, src);
}

// ---------------------------------------------------------------------------
// Aggregation: one wave per destination node, 4-way unrolled edge loop with
// next-group index prefetch -> 8 independent gathers in flight per wave.
// agg[z][n][:] = (1+eps) * x_dst[n][:] + sum_{e in CSR(n)} relu(x_src[src(e)] + ea[e])
// ---------------------------------------------------------------------------
__global__ __launch_bounds__(256)
void agg_k(const float* __restrict__ xa_base, long xa_ts,
           const float* __restrict__ xd_base, long xd_ts,
           const float* __restrict__ ea_ad, const float* __restrict__ ea_da,
           const float* __restrict__ eps_ad, const float* __restrict__ eps_da,
           const int* __restrict__ offs, const int2* __restrict__ pes,
           float* __restrict__ agg, int l) {
    int z = blockIdx.y, t = z >> 1, et = z & 1;
    int wv = threadIdx.x >> 6, lane = threadIdx.x & 63;
    int node = blockIdx.x * 4 + wv;
    if (node >= KN) return;

    const float* ea  = (et ? ea_da : ea_ad) + (long)t * KE * KH;
    const float* eps = et ? eps_da : eps_ad;
    const float* src = et ? (xd_base + t * xd_ts) : (xa_base + t * xa_ts);
    const float* dst = et ? (xa_base + t * xa_ts) : (xd_base + t * xd_ts);
    const int2*  pz  = pes + (long)z * KE;

    float scale = 1.0f + eps[t * KL + l];
    float2 acc0 = ((const float2*)(dst + (long)node * KH))[lane];
    acc0.x *= scale; acc0.y *= scale;
    float2 acc1 = make_float2(0.f, 0.f);

    int beg = offs[(long)z * (KN + 1) + node];
    int end = offs[(long)z * (KN + 1) + node + 1];
    int i = beg;
    int stop4 = beg + ((end - beg) & ~3);

    int2 p0, p1, p2, p3;
    if (i < stop4) { p0 = pz[i]; p1 = pz[i+1]; p2 = pz[i+2]; p3 = pz[i+3]; }
    while (i < stop4) {
        int inext = i + 4;
        int2 c0 = p0, c1 = p1, c2 = p2, c3 = p3;
        if (inext < stop4) { p0 = pz[inext]; p1 = pz[inext+1]; p2 = pz[inext+2]; p3 = pz[inext+3]; }
        float2 a0 = ((const float2*)(src + (long)c0.y * KH))[lane];
        float2 b0 = ((const float2*)(ea  + (long)c0.x * KH))[lane];
        float2 a1 = ((const float2*)(src + (long)c1.y * KH))[lane];
        float2 b1 = ((const float2*)(ea  + (long)c1.x * KH))[lane];
        float2 a2 = ((const float2*)(src + (long)c2.y * KH))[lane];
        float2 b2 = ((const float2*)(ea  + (long)c2.x * KH))[lane];
        float2 a3 = ((const float2*)(src + (long)c3.y * KH))[lane];
        float2 b3 = ((const float2*)(ea  + (long)c3.x * KH))[lane];
        acc0.x += fmaxf(a0.x + b0.x, 0.f); acc0.y += fmaxf(a0.y + b0.y, 0.f);
        acc1.x += fmaxf(a1.x + b1.x, 0.f); acc1.y += fmaxf(a1.y + b1.y, 0.f);
        acc0.x += fmaxf(a2.x + b2.x, 0.f); acc0.y += fmaxf(a2.y + b2.y, 0.f);
        acc1.x += fmaxf(a3.x + b3.x, 0.f); acc1.y += fmaxf(a3.y + b3.y, 0.f);
        i = inext;
    }
    for (; i < end; ++i) {
        int2 c = pz[i];
        float2 a = ((const float2*)(src + (long)c.y * KH))[lane];
        float2 b = ((const float2*)(ea  + (long)c.x * KH))[lane];
        acc0.x += fmaxf(a.x + b.x, 0.f); acc0.y += fmaxf(a.y + b.y, 0.f);
    }
    acc0.x += acc1.x; acc0.y += acc1.y;
    ((float2*)(agg + ((long)z * KN + node) * KH))[lane] = acc0;
}

// ---------------------------------------------------------------------------
// GEMM: out = [relu](H @ W + b).  H is (KN x 128) slice of agg for this z.
// mode 0: write in-place into agg.  mode 1: write to d_out region for (t, et).
// Tile: 128 rows x 128 cols per block, 256 threads, 8x8 micro-tile.
// W staged in 32-row chunks (16 KB) + transposed H chunk (16.9 KB) -> 33 KB
// LDS -> 4 blocks/CU (16 waves/CU) for latency hiding.
// ---------------------------------------------------------------------------
__global__ __launch_bounds__(256)
void gemm_k(const float* agg,
            const float* __restrict__ w_ad, const float* __restrict__ w_da,
            const float* __restrict__ b_ad, const float* __restrict__ b_da,
            float* out_agg, float* d_out,
            int l, int relu, int mode) {
    __shared__ float lw[32][KH];        // 16 KB
    __shared__ float hT[32][132];       // 16.9 KB, padded stride

    int z = blockIdx.y, t = z >> 1, et = z & 1;
    int tid = threadIdx.x;
    const float* W = (et ? w_da : w_ad) + (long)(t * KL + l) * KH * KH;
    const float* B = (et ? b_da : b_ad) + (long)(t * KL + l) * KH;
    const float* in = agg + (long)z * KN * KH;

    int r0 = blockIdx.x * 128;
    int tx = tid & 15, ty = tid >> 4;
    float acc[8][8];
    #pragma unroll
    for (int i = 0; i < 8; ++i)
        #pragma unroll
        for (int j = 0; j < 8; ++j) acc[i][j] = 0.0f;

    for (int kc = 0; kc < 4; ++kc) {
        // stage W chunk: rows kc*32 .. kc*32+31 (4096 floats, coalesced)
        #pragma unroll
        for (int i = 0; i < 4; ++i) {
            int idx = (i * 256 + tid) * 4;
            int kk = idx >> 7, col = idx & 127;
            *(float4*)&lw[kk][col] = *(const float4*)&W[(kc * 32 + kk) * KH + col];
        }
        // stage transposed H chunk: hT[k - kc*32][row]
        {
            int rr = tid >> 3, kg = tid & 7;
            int k = kc * 32 + kg * 4;
            #pragma unroll
            for (int p = 0; p < 4; ++p) {
                int row = p * 32 + rr;
                float4 v = make_float4(0.f, 0.f, 0.f, 0.f);
                if (r0 + row < KN) v = *(const float4*)&in[(long)(r0 + row) * KH + k];
                hT[kg * 4 + 0][row] = v.x;
                hT[kg * 4 + 1][row] = v.y;
                hT[kg * 4 + 2][row] = v.z;
                hT[kg * 4 + 3][row] = v.w;
            }
        }
        __syncthreads();
        #pragma unroll 4
        for (int kk = 0; kk < 32; ++kk) {
            float4 w0 = *(float4*)&lw[kk][tx * 8];
            float4 w1 = *(float4*)&lw[kk][tx * 8 + 4];
            float4 h0 = *(float4*)&hT[kk][ty * 8];
            float4 h1 = *(float4*)&hT[kk][ty * 8 + 4];
            float hv[8] = {h0.x, h0.y, h0.z, h0.w, h1.x, h1.y, h1.z, h1.w};
            float wv[8] = {w0.x, w0.y, w0.z, w0.w, w1.x, w1.y, w1.z, w1.w};
            #pragma unroll
            for (int i = 0; i < 8; ++i)
                #pragma unroll
                for (int j = 0; j < 8; ++j)
                    acc[i][j] = fmaf(hv[i], wv[j], acc[i][j]);
        }
        __syncthreads();
    }

    // epilogue
    float bias[8];
    #pragma unroll
    for (int j = 0; j < 8; ++j) bias[j] = B[tx * 8 + j];

    #pragma unroll
    for (int i = 0; i < 8; ++i) {
        int row = r0 + ty * 8 + i;
        if (row >= KN) continue;
        float v[8];
        #pragma unroll
        for (int j = 0; j < 8; ++j) {
            v[j] = acc[i][j] + bias[j];
            if (relu) v[j] = fmaxf(v[j], 0.0f);
        }
        float* orow;
        if (mode == 0) {
            orow = out_agg + ((long)z * KN + row) * KH;
        } else {
            long off = (long)t * KNT * KH + (et == 0 ? (long)KN * KH : 0) + (long)row * KH;
            orow = d_out + off;
        }
        *(float4*)&orow[tx * 8 + 0] = make_float4(v[0], v[1], v[2], v[3]);
        *(float4*)&orow[tx * 8 + 4] = make_float4(v[4], v[5], v[6], v[7]);
    }
}

// ---------------------------------------------------------------------------
extern "C" void kernel_launch(void* const* d_in, const int* in_sizes, int n_in,
                              void* d_out_v, int out_size, void* d_ws, size_t ws_size,
                              hipStream_t stream) {
    const float* x_a    = (const float*)d_in[0];
    const float* x_d    = (const float*)d_in[1];
    const float* ea_ad  = (const float*)d_in[2];
    const float* ea_da  = (const float*)d_in[3];
    const int*   ei_ad  = (const int*)d_in[4];
    const int*   ei_da  = (const int*)d_in[5];
    const float* w1_ad  = (const float*)d_in[6];
    const float* b1_ad  = (const float*)d_in[7];
    const float* w2_ad  = (const float*)d_in[8];
    const float* b2_ad  = (const float*)d_in[9];
    const float* eps_ad = (const float*)d_in[10];
    const float* w1_da  = (const float*)d_in[11];
    const float* b1_da  = (const float*)d_in[12];
    const float* w2_da  = (const float*)d_in[13];
    const float* b2_da  = (const float*)d_in[14];
    const float* eps_da = (const float*)d_in[15];
    float* out = (float*)d_out_v;

    // workspace layout
    float* agg  = (float*)d_ws;                          // 8 * KN * KH floats
    int*   offs = (int*)(agg + (size_t)8 * KN * KH);     // 8 * (KN+1)
    int*   cur  = offs + (size_t)8 * (KN + 1);           // 8 * KN
    int2*  pes  = (int2*)(cur + (size_t)8 * KN);         // 8 * KE int2

    // ---- build CSR (per z = t*2+et), valid for both layers ----
    hipMemsetAsync(cur, 0, (size_t)8 * KN * sizeof(int), stream);
    dim3 eg((KE + 255) / 256, 8);
    count_k<<<eg, 256, 0, stream>>>(ei_ad, ei_da, cur);
    scan_k<<<8, 256, 0, stream>>>(cur, offs);
    fill_k<<<eg, 256, 0, stream>>>(ei_ad, ei_da, cur, pes);

    dim3 ag((KN + 3) / 4, 8);
    dim3 gg((KN + 127) / 128, 8);

    for (int l = 0; l < KL; ++l) {
        const float* xab; long xats;
        const float* xdb; long xdts;
        if (l == 0) {
            xab = x_a; xats = (long)KN * KH;
            xdb = x_d; xdts = (long)KN * KH;
        } else {
            xab = out;                 xats = (long)KNT * KH;
            xdb = out + (long)KN * KH; xdts = (long)KNT * KH;
        }
        agg_k<<<ag, 256, 0, stream>>>(xab, xats, xdb, xdts,
                                      ea_ad, ea_da,
                                      eps_ad, eps_da, offs, pes, agg, l);
        // mid = relu(H @ w1 + b1), in-place into agg
        gemm_k<<<gg, 256, 0, stream>>>(agg, w1_ad, w1_da, b1_ad, b1_da,
                                       agg, out, l, 1, 0);
        // x_new = mid @ w2 + b2 (+relu between layers), into d_out
        gemm_k<<<gg, 256, 0, stream>>>(agg, w2_ad, w2_da, b2_ad, b2_da,
                                       agg, out, l, (l == 0) ? 1 : 0, 1);
    }
}

// Round 3
// 708.411 us; speedup vs baseline: 1.4478x; 1.0096x over previous
//
#include <hip/hip_runtime.h>

#define KT 4
#define KN 20000        // NA == ND == 20000
#define KE 100000
#define KH 128
#define KL 2
#define KNT 40000       // NA + ND

// ---------------------------------------------------------------------------
// CSR build: counts -> scan -> fill.  cursors array doubles as counts.
// fill stores packed (edge, src) pairs so agg needs no dependent index chase.
// ---------------------------------------------------------------------------
__global__ void count_k(const int* __restrict__ ei_ad, const int* __restrict__ ei_da,
                        int* __restrict__ cnt) {
    int e = blockIdx.x * 256 + threadIdx.x;
    int z = blockIdx.y;                 // z = t*2 + et
    if (e >= KE) return;
    int t = z >> 1, et = z & 1;
    const int* ei = et ? ei_da : ei_ad;
    int dst = ei[(t * 2 + 1) * KE + e];
    atomicAdd(&cnt[z * KN + dst], 1);
}

__global__ void scan_k(int* __restrict__ cnt, int* __restrict__ offs) {
    __shared__ int s[256];
    int z = blockIdx.x, tid = threadIdx.x;
    const int CH = (KN + 255) / 256;    // 79
    int n0 = tid * CH;
    int lim = n0 < KN ? min(CH, KN - n0) : 0;
    long base = (long)z * KN + n0;
    int sum = 0;
    for (int i = 0; i < lim; ++i) sum += cnt[base + i];
    s[tid] = sum;
    __syncthreads();
    for (int off = 1; off < 256; off <<= 1) {
        int v = (tid >= off) ? s[tid - off] : 0;
        __syncthreads();
        s[tid] += v;
        __syncthreads();
    }
    int run = s[tid] - sum;             // exclusive prefix
    for (int i = 0; i < lim; ++i) {
        int c = cnt[base + i];
        offs[(long)z * (KN + 1) + n0 + i] = run;
        cnt[base + i] = run;            // becomes fill cursor
        run += c;
    }
    if (tid == 0) offs[(long)z * (KN + 1) + KN] = KE;
}

__global__ void fill_k(const int* __restrict__ ei_ad, const int* __restrict__ ei_da,
                       int* __restrict__ cur, int2* __restrict__ pes) {
    int e = blockIdx.x * 256 + threadIdx.x;
    int z = blockIdx.y;
    if (e >= KE) return;
    int t = z >> 1, et = z & 1;
    const int* ei = et ? ei_da : ei_ad;
    int src = ei[(t * 2 + 0) * KE + e];
    int dst = ei[(t * 2 + 1) * KE + e];
    int pos = atomicAdd(&cur[z * KN + dst], 1);
    pes[(long)z * KE + pos] = make_int2(e, src);
}

// ---------------------------------------------------------------------------
// Aggregation: one wave per destination node.  The wave's two 32-lane halves
// each cover a full 128-float row (float4/lane); a batch of 8 edges
// (4 unrolled pairs, edge = i + 2u + half) issues all row gathers at once
// with clamped indices + predicated accumulate.  Halves combined by shfl_xor.
// agg[z][n][:] = (1+eps) * x_dst[n][:] + sum_e relu(x_src[src(e)] + ea[e])
// ---------------------------------------------------------------------------
__device__ __forceinline__ float4 relu_add4(float4 a, float4 b) {
    float4 r;
    r.x = fmaxf(a.x + b.x, 0.f);
    r.y = fmaxf(a.y + b.y, 0.f);
    r.z = fmaxf(a.z + b.z, 0.f);
    r.w = fmaxf(a.w + b.w, 0.f);
    return r;
}

__global__ __launch_bounds__(256)
void agg_k(const float* __restrict__ xa_base, long xa_ts,
           const float* __restrict__ xd_base, long xd_ts,
           const float* __restrict__ ea_ad, const float* __restrict__ ea_da,
           const float* __restrict__ eps_ad, const float* __restrict__ eps_da,
           const int* __restrict__ offs, const int2* __restrict__ pes,
           float* __restrict__ agg, int l) {
    int z = blockIdx.y, t = z >> 1, et = z & 1;
    int wv = threadIdx.x >> 6, lane = threadIdx.x & 63;
    int half = lane >> 5, li = lane & 31;
    int node = blockIdx.x * 4 + wv;
    if (node >= KN) return;

    const float* ea  = (et ? ea_da : ea_ad) + (long)t * KE * KH;
    const float* eps = et ? eps_da : eps_ad;
    const float* src = et ? (xd_base + t * xd_ts) : (xa_base + t * xa_ts);
    const float* dst = et ? (xa_base + t * xa_ts) : (xd_base + t * xd_ts);
    const int2*  pz  = pes + (long)z * KE;

    int beg = offs[(long)z * (KN + 1) + node];
    int end = offs[(long)z * (KN + 1) + node + 1];
    float scale = 1.0f + eps[t * KL + l];

    // issue dst-row load early (half 0 only)
    float4 dv = make_float4(0.f, 0.f, 0.f, 0.f);
    if (half == 0) dv = ((const float4*)(dst + (long)node * KH))[li];

    float4 acc = make_float4(0.f, 0.f, 0.f, 0.f);
    int last = end - 1;

    for (int i = beg; i < end; i += 8) {
        int e0 = i + 0 + half, e1 = i + 2 + half, e2 = i + 4 + half, e3 = i + 6 + half;
        int c0 = min(e0, last), c1 = min(e1, last), c2 = min(e2, last), c3 = min(e3, last);
        int2 p0 = pz[c0], p1 = pz[c1], p2 = pz[c2], p3 = pz[c3];
        float4 x0 = ((const float4*)(src + (long)p0.y * KH))[li];
        float4 g0 = ((const float4*)(ea  + (long)p0.x * KH))[li];
        float4 x1 = ((const float4*)(src + (long)p1.y * KH))[li];
        float4 g1 = ((const float4*)(ea  + (long)p1.x * KH))[li];
        float4 x2 = ((const float4*)(src + (long)p2.y * KH))[li];
        float4 g2 = ((const float4*)(ea  + (long)p2.x * KH))[li];
        float4 x3 = ((const float4*)(src + (long)p3.y * KH))[li];
        float4 g3 = ((const float4*)(ea  + (long)p3.x * KH))[li];
        float4 m0 = relu_add4(x0, g0);
        float4 m1 = relu_add4(x1, g1);
        float4 m2 = relu_add4(x2, g2);
        float4 m3 = relu_add4(x3, g3);
        if (e0 < end) { acc.x += m0.x; acc.y += m0.y; acc.z += m0.z; acc.w += m0.w; }
        if (e1 < end) { acc.x += m1.x; acc.y += m1.y; acc.z += m1.z; acc.w += m1.w; }
        if (e2 < end) { acc.x += m2.x; acc.y += m2.y; acc.z += m2.z; acc.w += m2.w; }
        if (e3 < end) { acc.x += m3.x; acc.y += m3.y; acc.z += m3.z; acc.w += m3.w; }
    }

    // combine the two halves (each covered the same feature slots)
    acc.x += __shfl_xor(acc.x, 32);
    acc.y += __shfl_xor(acc.y, 32);
    acc.z += __shfl_xor(acc.z, 32);
    acc.w += __shfl_xor(acc.w, 32);

    if (half == 0) {
        float4 r;
        r.x = scale * dv.x + acc.x;
        r.y = scale * dv.y + acc.y;
        r.z = scale * dv.z + acc.z;
        r.w = scale * dv.w + acc.w;
        ((float4*)(agg + ((long)z * KN + node) * KH))[li] = r;
    }
}

// ---------------------------------------------------------------------------
// GEMM: out = [relu](H @ W + b).  H is (KN x 128) slice of agg for this z.
// mode 0: write in-place into agg.  mode 1: write to d_out region for (t, et).
// Tile: 128 rows x 128 cols per block, 256 threads, 8x8 micro-tile.
// W staged in 32-row chunks (16 KB) + transposed H chunk (16.9 KB) -> 33 KB
// LDS -> 4 blocks/CU (16 waves/CU) for latency hiding.
// ---------------------------------------------------------------------------
__global__ __launch_bounds__(256)
void gemm_k(const float* agg,
            const float* __restrict__ w_ad, const float* __restrict__ w_da,
            const float* __restrict__ b_ad, const float* __restrict__ b_da,
            float* out_agg, float* d_out,
            int l, int relu, int mode) {
    __shared__ float lw[32][KH];        // 16 KB
    __shared__ float hT[32][132];       // 16.9 KB, padded stride

    int z = blockIdx.y, t = z >> 1, et = z & 1;
    int tid = threadIdx.x;
    const float* W = (et ? w_da : w_ad) + (long)(t * KL + l) * KH * KH;
    const float* B = (et ? b_da : b_ad) + (long)(t * KL + l) * KH;
    const float* in = agg + (long)z * KN * KH;

    int r0 = blockIdx.x * 128;
    int tx = tid & 15, ty = tid >> 4;
    float acc[8][8];
    #pragma unroll
    for (int i = 0; i < 8; ++i)
        #pragma unroll
        for (int j = 0; j < 8; ++j) acc[i][j] = 0.0f;

    for (int kc = 0; kc < 4; ++kc) {
        // stage W chunk: rows kc*32 .. kc*32+31 (4096 floats, coalesced)
        #pragma unroll
        for (int i = 0; i < 4; ++i) {
            int idx = (i * 256 + tid) * 4;
            int kk = idx >> 7, col = idx & 127;
            *(float4*)&lw[kk][col] = *(const float4*)&W[(kc * 32 + kk) * KH + col];
        }
        // stage transposed H chunk: hT[k - kc*32][row]
        {
            int rr = tid >> 3, kg = tid & 7;
            int k = kc * 32 + kg * 4;
            #pragma unroll
            for (int p = 0; p < 4; ++p) {
                int row = p * 32 + rr;
                float4 v = make_float4(0.f, 0.f, 0.f, 0.f);
                if (r0 + row < KN) v = *(const float4*)&in[(long)(r0 + row) * KH + k];
                hT[kg * 4 + 0][row] = v.x;
                hT[kg * 4 + 1][row] = v.y;
                hT[kg * 4 + 2][row] = v.z;
                hT[kg * 4 + 3][row] = v.w;
            }
        }
        __syncthreads();
        #pragma unroll 4
        for (int kk = 0; kk < 32; ++kk) {
            float4 w0 = *(float4*)&lw[kk][tx * 8];
            float4 w1 = *(float4*)&lw[kk][tx * 8 + 4];
            float4 h0 = *(float4*)&hT[kk][ty * 8];
            float4 h1 = *(float4*)&hT[kk][ty * 8 + 4];
            float hv[8] = {h0.x, h0.y, h0.z, h0.w, h1.x, h1.y, h1.z, h1.w};
            float wv[8] = {w0.x, w0.y, w0.z, w0.w, w1.x, w1.y, w1.z, w1.w};
            #pragma unroll
            for (int i = 0; i < 8; ++i)
                #pragma unroll
                for (int j = 0; j < 8; ++j)
                    acc[i][j] = fmaf(hv[i], wv[j], acc[i][j]);
        }
        __syncthreads();
    }

    // epilogue
    float bias[8];
    #pragma unroll
    for (int j = 0; j < 8; ++j) bias[j] = B[tx * 8 + j];

    #pragma unroll
    for (int i = 0; i < 8; ++i) {
        int row = r0 + ty * 8 + i;
        if (row >= KN) continue;
        float v[8];
        #pragma unroll
        for (int j = 0; j < 8; ++j) {
            v[j] = acc[i][j] + bias[j];
            if (relu) v[j] = fmaxf(v[j], 0.0f);
        }
        float* orow;
        if (mode == 0) {
            orow = out_agg + ((long)z * KN + row) * KH;
        } else {
            long off = (long)t * KNT * KH + (et == 0 ? (long)KN * KH : 0) + (long)row * KH;
            orow = d_out + off;
        }
        *(float4*)&orow[tx * 8 + 0] = make_float4(v[0], v[1], v[2], v[3]);
        *(float4*)&orow[tx * 8 + 4] = make_float4(v[4], v[5], v[6], v[7]);
    }
}

// ---------------------------------------------------------------------------
extern "C" void kernel_launch(void* const* d_in, const int* in_sizes, int n_in,
                              void* d_out_v, int out_size, void* d_ws, size_t ws_size,
                              hipStream_t stream) {
    const float* x_a    = (const float*)d_in[0];
    const float* x_d    = (const float*)d_in[1];
    const float* ea_ad  = (const float*)d_in[2];
    const float* ea_da  = (const float*)d_in[3];
    const int*   ei_ad  = (const int*)d_in[4];
    const int*   ei_da  = (const int*)d_in[5];
    const float* w1_ad  = (const float*)d_in[6];
    const float* b1_ad  = (const float*)d_in[7];
    const float* w2_ad  = (const float*)d_in[8];
    const float* b2_ad  = (const float*)d_in[9];
    const float* eps_ad = (const float*)d_in[10];
    const float* w1_da  = (const float*)d_in[11];
    const float* b1_da  = (const float*)d_in[12];
    const float* w2_da  = (const float*)d_in[13];
    const float* b2_da  = (const float*)d_in[14];
    const float* eps_da = (const float*)d_in[15];
    float* out = (float*)d_out_v;

    // workspace layout
    float* agg  = (float*)d_ws;                          // 8 * KN * KH floats
    int*   offs = (int*)(agg + (size_t)8 * KN * KH);     // 8 * (KN+1)
    int*   cur  = offs + (size_t)8 * (KN + 1);           // 8 * KN
    int2*  pes  = (int2*)(cur + (size_t)8 * KN);         // 8 * KE int2

    // ---- build CSR (per z = t*2+et), valid for both layers ----
    hipMemsetAsync(cur, 0, (size_t)8 * KN * sizeof(int), stream);
    dim3 eg((KE + 255) / 256, 8);
    count_k<<<eg, 256, 0, stream>>>(ei_ad, ei_da, cur);
    scan_k<<<8, 256, 0, stream>>>(cur, offs);
    fill_k<<<eg, 256, 0, stream>>>(ei_ad, ei_da, cur, pes);

    dim3 ag((KN + 3) / 4, 8);
    dim3 gg((KN + 127) / 128, 8);

    for (int l = 0; l < KL; ++l) {
        const float* xab; long xats;
        const float* xdb; long xdts;
        if (l == 0) {
            xab = x_a; xats = (long)KN * KH;
            xdb = x_d; xdts = (long)KN * KH;
        } else {
            xab = out;                 xats = (long)KNT * KH;
            xdb = out + (long)KN * KH; xdts = (long)KNT * KH;
        }
        agg_k<<<ag, 256, 0, stream>>>(xab, xats, xdb, xdts,
                                      ea_ad, ea_da,
                                      eps_ad, eps_da, offs, pes, agg, l);
        // mid = relu(H @ w1 + b1), in-place into agg
        gemm_k<<<gg, 256, 0, stream>>>(agg, w1_ad, w1_da, b1_ad, b1_da,
                                       agg, out, l, 1, 0);
        // x_new = mid @ w2 + b2 (+relu between layers), into d_out
        gemm_k<<<gg, 256, 0, stream>>>(agg, w2_ad, w2_da, b2_ad, b2_da,
                                       agg, out, l, (l == 0) ? 1 : 0, 1);
    }
}